// Round 3
// baseline (390.866 us; speedup 1.0000x reference)
//
#include <hip/hip_runtime.h>
#include <hip/hip_bf16.h>
#include <stdint.h>

// Problem constants
#define NB   8
#define KL   512
#define QD   16
#define SD   128
#define ED   256
#define RPN  (QD*SD)   // 2048 rows (q,s) per n
#define TR   16        // rows per fused-attention block

typedef __hip_bfloat16 bf16;

__device__ __forceinline__ float b2f(unsigned short u){
    union { uint32_t i; float f; } v; v.i = ((uint32_t)u) << 16; return v.f;
}
__device__ __forceinline__ unsigned short f2b(float f){
    union { float ff; uint32_t i; } v; v.ff = f;
    uint32_t lsb = (v.i >> 16) & 1;
    v.i += 0x7FFFu + lsb;               // RNE
    return (unsigned short)(v.i >> 16);
}

template<bool B>
__device__ __forceinline__ float ldin(const void* p, size_t i){
    if (B) return b2f(((const unsigned short*)p)[i]);
    else   return ((const float*)p)[i];
}

// ---------------- dtype probe ----------------
// bf16 mode: bits[14:7] of each 32b word = exponent field of the LOW bf16
// element -> concentrated in [120,132] for N(0,1) data (>99%).
// fp32 mode: those bits are mid-mantissa bits -> ~5% hit rate.
__global__ void k_probe(const uint32_t* __restrict__ w, int* __restrict__ flag){
    __shared__ int cnt;
    if (threadIdx.x == 0) cnt = 0;
    __syncthreads();
    int local = 0;
    #pragma unroll
    for (int i = 0; i < 4; ++i){
        uint32_t x = w[threadIdx.x*4 + i];
        uint32_t e = (x >> 7) & 0xFFu;
        local += (e >= 120u && e <= 132u) ? 1 : 0;
    }
    atomicAdd(&cnt, local);
    __syncthreads();
    if (threadIdx.x == 0) *flag = (cnt > 512) ? 1 : 0;
}

// ---------------- weight prep ----------------
// wos[e*256+d] = sum_h Wo[e*2048 + h*256 + d]
template<bool B>
__global__ void k_wosum(const void* __restrict__ Wo, const int* __restrict__ flag,
                        float* __restrict__ wos){
    if (*flag != (B ? 1 : 0)) return;
    int idx = blockIdx.x*256 + threadIdx.x;   // e*256+d
    int e = idx >> 8, d = idx & 255;
    float s = 0.f;
    #pragma unroll
    for (int h = 0; h < 8; ++h) s += ldin<B>(Wo, (size_t)e*2048 + h*256 + d);
    wos[idx] = s;
}

// Gt[b*256+a] = G[a,b] = sum_d Wq[d,a]*Wk[d,b]
template<bool B>
__global__ void k_gt(const void* __restrict__ Wq, const void* __restrict__ Wk,
                     const int* __restrict__ flag, float* __restrict__ Gt){
    if (*flag != (B ? 1 : 0)) return;
    int b = blockIdx.x, a = threadIdx.x;
    float s = 0.f;
    for (int d = 0; d < 256; ++d)
        s += ldin<B>(Wq, (size_t)d*256 + a) * ldin<B>(Wk, (size_t)d*256 + b);
    Gt[b*256 + a] = s;
}

// Mt[d*256+e] = M[e,d] = sum_dp wos[e*256+dp]*Wv[dp*256+d]
template<bool B>
__global__ void k_mt(const float* __restrict__ wos, const void* __restrict__ Wv,
                     const int* __restrict__ flag, float* __restrict__ Mt){
    if (*flag != (B ? 1 : 0)) return;
    int d = blockIdx.x, e = threadIdx.x;
    float s = 0.f;
    for (int dp = 0; dp < 256; ++dp)
        s += wos[e*256 + dp] * ldin<B>(Wv, (size_t)dp*256 + d);
    Mt[d*256 + e] = s;
}

// ---------------- projections: C[r,o] = sum_i A[r,i] * Wt[i*256+o] ----------
// A: [Rtot,256] row-major (dtype per flag). C stored bf16 (our ws).
template<bool B>
__global__ __launch_bounds__(256)
void k_proj(const void* __restrict__ A, const float* __restrict__ Wt,
            const int* __restrict__ flag, unsigned short* __restrict__ C){
    if (*flag != (B ? 1 : 0)) return;
    __shared__ float As[8][256];
    int r0 = blockIdx.x * 8;
    int t  = threadIdx.x;
    #pragma unroll
    for (int j = 0; j < 8; ++j)
        As[j][t] = ldin<B>(A, (size_t)(r0 + j)*256 + t);
    __syncthreads();
    float acc[8] = {0,0,0,0,0,0,0,0};
    for (int i = 0; i < 256; ++i){
        float w = Wt[i*256 + t];
        #pragma unroll
        for (int j = 0; j < 8; ++j) acc[j] += As[j][i] * w;
    }
    #pragma unroll
    for (int j = 0; j < 8; ++j)
        C[(size_t)(r0 + j)*256 + t] = f2b(acc[j]);
}

// ---------------- fused: energy -> masked softmax -> PV -> +bo --------------
template<bool B>
__global__ __launch_bounds__(256)
void k_fused(const void* __restrict__ query, const unsigned short* __restrict__ kk,
             const unsigned short* __restrict__ u, const int* __restrict__ mask,
             const void* __restrict__ bo, const int* __restrict__ flag,
             void* __restrict__ out){
    if (*flag != (B ? 1 : 0)) return;
    int n  = blockIdx.y;
    int r0 = blockIdx.x * TR;
    const unsigned short* Kn = kk + (size_t)n*KL*ED;
    const unsigned short* Un = u  + (size_t)n*KL*ED;
    const int* mn = mask + n*KL;

    __shared__ float Qs[TR][ED];        // 16 KB
    __shared__ float Sc[TR][KL + 2];    // 32.9 KB (rows stay 8B aligned)
    __shared__ float invs[TR];

    int t = threadIdx.x;

    // ---- phase 1: Q tile -> LDS ----
    #pragma unroll
    for (int j = 0; j < TR; ++j)
        Qs[j][t] = ldin<B>(query, (size_t)n*RPN*ED + (size_t)(r0 + j)*ED + t);
    __syncthreads();

    // ---- phase 2: scores for k1=t, k2=t+256 ----
    {
        const unsigned short* kr1 = Kn + (size_t)t*ED;
        const unsigned short* kr2 = Kn + (size_t)(t + 256)*ED;
        float acc1[TR] = {}, acc2[TR] = {};
        for (int a = 0; a < ED; a += 4){
            ushort4 h1 = *(const ushort4*)(kr1 + a);
            ushort4 h2 = *(const ushort4*)(kr2 + a);
            float k10 = b2f(h1.x), k11 = b2f(h1.y), k12 = b2f(h1.z), k13 = b2f(h1.w);
            float k20 = b2f(h2.x), k21 = b2f(h2.y), k22 = b2f(h2.z), k23 = b2f(h2.w);
            #pragma unroll
            for (int r = 0; r < TR; ++r){
                float4 qv = *(const float4*)(&Qs[r][a]);   // LDS broadcast
                acc1[r] += qv.x*k10 + qv.y*k11 + qv.z*k12 + qv.w*k13;
                acc2[r] += qv.x*k20 + qv.y*k21 + qv.z*k22 + qv.w*k23;
            }
        }
        bool z1 = (mn[t] == 0), z2 = (mn[t + 256] == 0);
        #pragma unroll
        for (int r = 0; r < TR; ++r){
            Sc[r][t]       = z1 ? -1e20f : acc1[r] * 0.0625f;
            Sc[r][t + 256] = z2 ? -1e20f : acc2[r] * 0.0625f;
        }
    }
    __syncthreads();

    // ---- phase 2.5: masked softmax per row (16 threads/row) ----
    {
        int row = t >> 4, l16 = t & 15;
        float xs[32];
        float m = -3.0e38f;
        #pragma unroll
        for (int i = 0; i < 32; ++i){
            xs[i] = Sc[row][l16 + 16*i];
            m = fmaxf(m, xs[i]);
        }
        #pragma unroll
        for (int off = 1; off < 16; off <<= 1)
            m = fmaxf(m, __shfl_xor(m, off, 16));
        float s = 0.f;
        #pragma unroll
        for (int i = 0; i < 32; ++i){
            float p = __expf(xs[i] - m);
            s += p;
            Sc[row][l16 + 16*i] = p;
        }
        #pragma unroll
        for (int off = 1; off < 16; off <<= 1)
            s += __shfl_xor(s, off, 16);
        if (l16 == 0) invs[row] = 1.0f / s;
    }
    __syncthreads();

    // ---- phase 3: PV. wave owns 4 rows; lane owns 4 e's ----
    {
        int e0    = (t & 63) * 4;
        int rbase = (t >> 6) * 4;
        float acc[4][4] = {};
        for (int k = 0; k < KL; k += 2){
            float2 p[4];
            #pragma unroll
            for (int j = 0; j < 4; ++j)
                p[j] = *(const float2*)(&Sc[rbase + j][k]);
            ushort4 h0 = *(const ushort4*)(Un + (size_t)k*ED + e0);
            ushort4 h1 = *(const ushort4*)(Un + (size_t)(k + 1)*ED + e0);
            float u00 = b2f(h0.x), u01 = b2f(h0.y), u02 = b2f(h0.z), u03 = b2f(h0.w);
            float u10 = b2f(h1.x), u11 = b2f(h1.y), u12 = b2f(h1.z), u13 = b2f(h1.w);
            #pragma unroll
            for (int j = 0; j < 4; ++j){
                acc[j][0] += p[j].x*u00 + p[j].y*u10;
                acc[j][1] += p[j].x*u01 + p[j].y*u11;
                acc[j][2] += p[j].x*u02 + p[j].y*u12;
                acc[j][3] += p[j].x*u03 + p[j].y*u13;
            }
        }
        #pragma unroll
        for (int j = 0; j < 4; ++j){
            float inv = invs[rbase + j];
            #pragma unroll
            for (int c = 0; c < 4; ++c){
                float val = acc[j][c] * inv + ldin<B>(bo, e0 + c);
                size_t oidx = (size_t)n*RPN*ED + (size_t)(r0 + rbase + j)*ED + e0 + c;
                if (B) ((unsigned short*)out)[oidx] = f2b(val);
                else   ((float*)out)[oidx] = val;
            }
        }
    }
}

// ---------------- launch ----------------
extern "C" void kernel_launch(void* const* d_in, const int* in_sizes, int n_in,
                              void* d_out, int out_size, void* d_ws, size_t ws_size,
                              hipStream_t stream){
    const void* values = d_in[0];
    const void* keys   = d_in[1];
    const void* query  = d_in[2];
    const int*  mask   = (const int*)d_in[3];
    const void* Wv     = d_in[4];
    const void* Wk     = d_in[5];
    const void* Wq     = d_in[6];
    const void* Wo     = d_in[7];
    const void* bo     = d_in[8];

    // ws layout (floats): [flag pad 64][wos 65536][gt 65536][mt 65536]
    //                     [kk bf16 1Mi elem = 524288 f][u bf16 = 524288 f]
    float* ws = (float*)d_ws;
    int*   ws_flag = (int*)ws;
    float* ws_wos  = ws + 64;
    float* ws_gt   = ws + 64 + 65536;
    float* ws_mt   = ws + 64 + 131072;
    unsigned short* ws_kk = (unsigned short*)(ws + 64 + 196608);
    unsigned short* ws_u  = ws_kk + (size_t)NB*KL*ED;   // total ~4.98 MB

    k_probe<<<1, 256, 0, stream>>>((const uint32_t*)values, ws_flag);

    k_wosum<true ><<<256, 256, 0, stream>>>(Wo, ws_flag, ws_wos);
    k_wosum<false><<<256, 256, 0, stream>>>(Wo, ws_flag, ws_wos);
    k_gt   <true ><<<256, 256, 0, stream>>>(Wq, Wk, ws_flag, ws_gt);
    k_gt   <false><<<256, 256, 0, stream>>>(Wq, Wk, ws_flag, ws_gt);
    k_mt   <true ><<<256, 256, 0, stream>>>(ws_wos, Wv, ws_flag, ws_mt);
    k_mt   <false><<<256, 256, 0, stream>>>(ws_wos, Wv, ws_flag, ws_mt);

    k_proj <true ><<<512, 256, 0, stream>>>(keys,   ws_gt, ws_flag, ws_kk);
    k_proj <false><<<512, 256, 0, stream>>>(keys,   ws_gt, ws_flag, ws_kk);
    k_proj <true ><<<512, 256, 0, stream>>>(values, ws_mt, ws_flag, ws_u);
    k_proj <false><<<512, 256, 0, stream>>>(values, ws_mt, ws_flag, ws_u);

    k_fused<true ><<<dim3(RPN/TR, NB), 256, 0, stream>>>(query, ws_kk, ws_u, mask, bo, ws_flag, d_out);
    k_fused<false><<<dim3(RPN/TR, NB), 256, 0, stream>>>(query, ws_kk, ws_u, mask, bo, ws_flag, d_out);
}